// Round 1
// 232.638 us; speedup vs baseline: 1.0148x; 1.0148x over previous
//
#include <hip/hip_runtime.h>

// ROI bilinear pooling (tf.image.resize half-pixel centers), POOL=7.
// img: (1, 64, 64, 1024) fp32, NHWC. rois: (1, R, 4) int32 = [x, y, w, h].
// out: (1, R, 7, 7, 1024) fp32.
//
// R5 = R4 row kernel + spatial ROI ordering (ONE change).
// Theory: kernel (~114us of the 236us; rest is harness poison-fill) is
// bound by HBM *reads*: random ROI order gives zero cross-ROI locality,
// so ~330 MB of distinct-pixel traffic misses L2 (4MB/XCD vs 16.7MB img)
// and mixes with the 205 MB write stream at HBM. Each image pixel is
// needed ~20x across ROIs — counting-sort ROIs by y (3us, one block) and
// the existing chunked-XCD mapping turns that reuse into L2 hits: each
// XCD sweeps a contiguous ~22-row y-band (~5.6 MB, rolling window less).
// Pool kernel is otherwise byte-identical to R4 (plain stores).

#define POOLSZ 7
#define IMG_H 64
#define IMG_W 64
#define IMG_C 1024
#define NUM_XCD 8

typedef float v4f __attribute__((ext_vector_type(4)));

// Kernel A: counting-sort ROI indices by y into order[] (workspace).
// R is small (1024): one block, 64-bin LDS counting sort, ~3 us.
__global__ __launch_bounds__(256) void roi_sort_kernel(
    const int* __restrict__ rois, int* __restrict__ order, int R) {
    __shared__ int cnt[64];
    __shared__ int ofs[64];
    const int t = threadIdx.x;
    if (t < 64) cnt[t] = 0;
    __syncthreads();
    for (int r = t; r < R; r += 256) {
        const int y = rois[r * 4 + 1] & 63;
        atomicAdd(&cnt[y], 1);
    }
    __syncthreads();
    if (t == 0) {
        int s = 0;
        for (int i = 0; i < 64; ++i) { ofs[i] = s; s += cnt[i]; }
    }
    __syncthreads();
    for (int r = t; r < R; r += 256) {
        const int y = rois[r * 4 + 1] & 63;
        const int p = atomicAdd(&ofs[y], 1);
        order[p] = r;   // permutation of 0..R-1 by construction
    }
}

// One block per (roi, py) row: 7 output cells. 256 threads, each owns a
// float4 channel slice, issues all 28 bilinear taps up-front, blends,
// stores 7 outputs (each wave store = 1 KB contiguous).
__global__ __launch_bounds__(256, 1) void roi_pool_row_kernel(
    const float* __restrict__ img,
    const int* __restrict__ rois,
    float* __restrict__ out,
    int roisPerXcd,              // R/8 when R%8==0, else 0 (identity mapping)
    const int* __restrict__ order) {  // y-sorted ROI permutation, or null
    int rIdx, py;
    if (roisPerXcd > 0) {
        // xcd = blockIdx % 8; chunk ROIs per XCD for L2 locality.
        const int xcd   = blockIdx.x & (NUM_XCD - 1);
        const int local = blockIdx.x >> 3;           // 0 .. R/8*7-1
        rIdx = xcd * roisPerXcd + local / POOLSZ;
        py   = local % POOLSZ;
    } else {
        rIdx = blockIdx.x / POOLSZ;
        py   = blockIdx.x % POOLSZ;
    }
    const int r = order ? order[rIdx] : rIdx;   // spatial (y-band) ordering

    const int4 roi = ((const int4*)rois)[r];
    const int rx = roi.x, ry = roi.y, rw = roi.z, rh = roi.w;

    // y coords: src = (py+0.5)*h/7 - 0.5; lerp from unclipped floor (ref semantics)
    const float scy  = (float)rh * (1.0f / (float)POOLSZ);
    const float srcy = ((float)py + 0.5f) * scy - 0.5f;
    const float fy   = floorf(srcy);
    const float ty   = srcy - fy;
    const int   iy   = (int)fy;
    const int   y0   = ry + min(max(iy,     0), rh - 1);
    const int   y1   = ry + min(max(iy + 1, 0), rh - 1);

    // x coords for all 7 cells
    int   x0[POOLSZ], x1[POOLSZ];
    float tx[POOLSZ];
    const float scx = (float)rw * (1.0f / (float)POOLSZ);
#pragma unroll
    for (int px = 0; px < POOLSZ; ++px) {
        const float srcx = ((float)px + 0.5f) * scx - 0.5f;
        const float fx   = floorf(srcx);
        tx[px] = srcx - fx;
        const int ix = (int)fx;
        x0[px] = rx + min(max(ix,     0), rw - 1);
        x1[px] = rx + min(max(ix + 1, 0), rw - 1);
    }

    const int c4 = threadIdx.x;  // 0..255: float4 channel slice
    const v4f* row0 = (const v4f*)(img + (size_t)y0 * IMG_W * IMG_C) + c4;
    const v4f* row1 = (const v4f*)(img + (size_t)y1 * IMG_W * IMG_C) + c4;

    // Issue all 28 loads before any arithmetic (deep MLP).
    v4f a[POOLSZ], b[POOLSZ], c[POOLSZ], d[POOLSZ];
#pragma unroll
    for (int px = 0; px < POOLSZ; ++px) {
        a[px] = row0[(size_t)x0[px] * (IMG_C / 4)];
        b[px] = row0[(size_t)x1[px] * (IMG_C / 4)];
        c[px] = row1[(size_t)x0[px] * (IMG_C / 4)];
        d[px] = row1[(size_t)x1[px] * (IMG_C / 4)];
    }

    // out = (a*(1-tx)+b*tx)*(1-ty) + (c*(1-tx)+d*tx)*ty
    v4f* dst = (v4f*)out + ((size_t)r * POOLSZ + py) * POOLSZ * (IMG_C / 4) + c4;
#pragma unroll
    for (int px = 0; px < POOLSZ; ++px) {
        const v4f top = a[px] + (b[px] - a[px]) * tx[px];
        const v4f bot = c[px] + (d[px] - c[px]) * tx[px];
        const v4f o   = top + (bot - top) * ty;
        dst[(size_t)px * (IMG_C / 4)] = o;   // plain store
    }
}

extern "C" void kernel_launch(void* const* d_in, const int* in_sizes, int n_in,
                              void* d_out, int out_size, void* d_ws, size_t ws_size,
                              hipStream_t stream) {
    const float* img  = (const float*)d_in[0];
    const int*   rois = (const int*)d_in[1];
    float*       out  = (float*)d_out;
    const int R = in_sizes[1] / 4;                  // rois: (1, R, 4)
    const int n_rows = R * POOLSZ;                  // 1024*7 = 7168 blocks
    const int roisPerXcd = (R % NUM_XCD == 0) ? (R / NUM_XCD) : 0;

    int* order = nullptr;
    if (ws_size >= (size_t)R * sizeof(int)) {
        order = (int*)d_ws;
        roi_sort_kernel<<<1, 256, 0, stream>>>(rois, order, R);
    }
    roi_pool_row_kernel<<<n_rows, 256, 0, stream>>>(img, rois, out, roisPerXcd, order);
}